// Round 11
// baseline (66.270 us; speedup 1.0000x reference)
//
#include <hip/hip_runtime.h>
#include <hip/hip_bf16.h>
#include <cstddef>

// B=8, L=1024, E=1024, H=8, d=128
// out = BandedGaussianAttn(values @ Win^T) @ Wout^T
// Identity (R4..R10-proven): equal stds -> smoothing commutes with projection;
// per-head offset = row shift of GEMM1's A operand (BN=128 == one head).
// Pipeline:
//   smooth16: 9-tap smoothing fp32->bf16 (4 rows x 8 cols/thread, 16B stores)
//             + weight cvt tail blocks
//   GEMM1: Attb = VG(shifted rows) @ Winb^T  bf16->bf16  (4-phase fine pipe)
//   GEMM2: out  = Attb @ Woutb^T             bf16->fp32

#define BATCH 8
#define SEQL  1024
#define EMB   1024
#define VROWS 1040   // 130 x 8; VG row r holds smoothed source p = r-4

typedef unsigned short u16;
typedef __attribute__((ext_vector_type(8))) short s16x8;
typedef __attribute__((ext_vector_type(4))) float f32x4;
typedef __attribute__((ext_vector_type(8))) unsigned short u16x8;

#define GLOAD_LDS16(g, l)                                                     \
    __builtin_amdgcn_global_load_lds(                                         \
        (const __attribute__((address_space(1))) void*)(g),                   \
        (__attribute__((address_space(3))) void*)(l), 16, 0, 0)

__device__ __forceinline__ u16 f2bf(float f) {
    unsigned u = __builtin_bit_cast(unsigned, f);
    u += 0x7FFF + ((u >> 16) & 1);
    return (u16)(u >> 16);
}

__constant__ int c_ofs[8] = { -3, -2, -1, 0, 0, 1, 2, 3 };

// ---------- smooth16: 9-tap smoothing, 4 rows x 8 cols per thread ----------
// blocks [0, 1040): b = blk&7, gg = blk>>3 -> VG rows gg*8 + (tid>>7)*4 .. +3.
//   12 covering input rows, branchless clamped loads (R9/R10-proven pattern),
//   constexpr tap weights (inline literals), u16x8 (16B) stores.
// blocks [1040, 2064): fp32->bf16 cvt of Win/Wout.
__global__ __launch_bounds__(256) void smooth16(
    const float* __restrict__ values, const unsigned char* __restrict__ mask,
    const float* __restrict__ wi, const float* __restrict__ wo,
    u16* __restrict__ VG, u16* __restrict__ wib, u16* __restrict__ wob)
{
    constexpr float W[9] = {
        1.3383022576488537e-04f, 4.431848411938008e-03f, 5.399096651318806e-02f,
        2.4197072451914337e-01f, 3.989422804014327e-01f, 2.4197072451914337e-01f,
        5.399096651318806e-02f,  4.431848411938008e-03f, 1.3383022576488537e-04f
    };
    const int blk = blockIdx.x;
    const int NSM = BATCH * (VROWS / 8);         // 1040
    if (blk < NSM) {
        const int b   = blk & 7;
        const int gg  = blk >> 3;                // 0..129
        const int sub = threadIdx.x >> 7;        // 0..1
        const int r0  = gg * 8 + sub * 4;        // VG rows r0..r0+3
        const int ct  = (threadIdx.x & 127) * 8;
        const float* vb = values + (size_t)b * SEQL * EMB + ct;
        const unsigned char* mrow = mask + b * SEQL;

        f32x4 accA[4] = {}, accB[4] = {};
        #pragma unroll
        for (int i = 0; i < 12; ++i) {           // input rows v = r0-8+i
            const int v  = r0 - 8 + i;
            const int vc = v < 0 ? 0 : (v > SEQL - 1 ? SEQL - 1 : v);
            const float f = ((unsigned)v < (unsigned)SEQL && !mrow[vc]) ? 1.f : 0.f;
            const float4 xA = *(const float4*)(vb + (size_t)vc * EMB);
            const float4 xB = *(const float4*)(vb + (size_t)vc * EMB + 4);
            const float a0 = xA.x * f, a1 = xA.y * f, a2 = xA.z * f, a3 = xA.w * f;
            const float b0 = xB.x * f, b1 = xB.y * f, b2 = xB.z * f, b3 = xB.w * f;
            #pragma unroll
            for (int k = 0; k < 4; ++k) {
                const int j = i - k;             // compile-time tap index
                if (j < 0 || j > 8) continue;    // resolved at compile time
                const float w = W[j];
                accA[k][0] = fmaf(w, a0, accA[k][0]);
                accA[k][1] = fmaf(w, a1, accA[k][1]);
                accA[k][2] = fmaf(w, a2, accA[k][2]);
                accA[k][3] = fmaf(w, a3, accA[k][3]);
                accB[k][0] = fmaf(w, b0, accB[k][0]);
                accB[k][1] = fmaf(w, b1, accB[k][1]);
                accB[k][2] = fmaf(w, b2, accB[k][2]);
                accB[k][3] = fmaf(w, b3, accB[k][3]);
            }
        }
        u16* og = VG + (size_t)(b * VROWS + r0) * EMB + ct;
        #pragma unroll
        for (int k = 0; k < 4; ++k) {
            u16x8 o;
            o[0] = f2bf(accA[k][0]); o[1] = f2bf(accA[k][1]);
            o[2] = f2bf(accA[k][2]); o[3] = f2bf(accA[k][3]);
            o[4] = f2bf(accB[k][0]); o[5] = f2bf(accB[k][1]);
            o[6] = f2bf(accB[k][2]); o[7] = f2bf(accB[k][3]);
            *(u16x8*)(og + (size_t)k * EMB) = o;
        }
    } else {
        const int k = (blk - NSM) * 256 + threadIdx.x;   // 0..262143
        const float* src = (k < 131072) ? wi : wo;
        u16* dst = (k < 131072) ? wib : wob;
        const size_t off = (size_t)(k & 131071) * 8;
        const float4 a = *(const float4*)(src + off);
        const float4 b4 = *(const float4*)(src + off + 4);
        u16x8 o;
        o[0] = f2bf(a.x);  o[1] = f2bf(a.y);  o[2] = f2bf(a.z);  o[3] = f2bf(a.w);
        o[4] = f2bf(b4.x); o[5] = f2bf(b4.y); o[6] = f2bf(b4.z); o[7] = f2bf(b4.w);
        *(u16x8*)(dst + off) = o;
    }
}

// ---------- pipelined bf16 MFMA GEMM: C[M,N] = A[M,K]*B[N,K]^T ----------
// BM=256 BN=128 BK=64, 512 thr / 8 waves (4M x 2N, per-wave 64x64).
// 3-buffer LDS, **4 fine phases per K-tile** (8 MFMAs each), vmcnt(6)
// counted at P3 only, T2 XOR-chunk swizzle, T5 setprio, T1 XCD swizzle.
constexpr int BM = 256, BN = 128, BK = 64;
constexpr int A_EL = BM * BK;
constexpr int B_EL = BN * BK;
constexpr int BUF_EL = A_EL + B_EL;      // 48 KB x3 = 144 KB

template <bool OUT_BF16, bool SHIFTED>
__global__ __launch_bounds__(512, 2) void gemm_nt_pipe(
    const u16* __restrict__ A, const u16* __restrict__ B,
    void* __restrict__ Cout, int M, int N, int K)
{
    __shared__ u16 lds[3 * BUF_EL];

    const int tid  = threadIdx.x;
    const int lane = tid & 63;
    const int wave = tid >> 6;

    const int nwg = gridDim.x;
    const int bid = blockIdx.x;
    const int swz = (bid & 7) * (nwg >> 3) + (bid >> 3);
    const int ntn = N >> 7;
    const int row0 = (swz / ntn) * BM;
    const int col0 = (swz % ntn) * BN;

    int arow0;
    if (SHIFTED) {
        const int b  = row0 >> 10;            // BM=256 | 1024: no batch straddle
        const int q0 = row0 & (SEQL - 1);
        arow0 = b * VROWS + q0 + 4 + c_ofs[col0 >> 7];
    } else {
        arow0 = row0;
    }
    const u16* Ab = A + (size_t)arow0 * K;
    const u16* Bb = B + (size_t)col0 * K;

    const int wm = wave >> 1;    // 0..3 (M quarter)
    const int wn = wave & 1;     // 0..1 (N half)
    const int fr = lane & 15;
    const int fg = lane >> 4;

    const int srow   = tid >> 3;
    const int schunk = tid & 7;

    f32x4 acc[4][4] = {};

    auto stageA3 = [&](int bsel, int kt) {
        u16* Abuf = lds + bsel * BUF_EL;
        const int k0 = kt << 6;
        #pragma unroll
        for (int c = 0; c < 3; ++c) {
            const int row = c * 64 + srow;
            const int sc  = (schunk ^ (row & 7)) << 3;
            GLOAD_LDS16(Ab + (size_t)row * K + k0 + sc, Abuf + c * 4096 + wave * 512);
        }
    };
    auto stageRest = [&](int bsel, int kt) {
        u16* Abuf = lds + bsel * BUF_EL;
        u16* Bbuf = Abuf + A_EL;
        const int k0 = kt << 6;
        {
            const int row = 192 + srow;
            const int sc  = (schunk ^ (row & 7)) << 3;
            GLOAD_LDS16(Ab + (size_t)row * K + k0 + sc, Abuf + 3 * 4096 + wave * 512);
        }
        #pragma unroll
        for (int c = 0; c < 2; ++c) {
            const int row = c * 64 + srow;
            const int sc  = (schunk ^ (row & 7)) << 3;
            GLOAD_LDS16(Bb + (size_t)row * K + k0 + sc, Bbuf + c * 4096 + wave * 512);
        }
    };

    // one K-tile, 4 fine phases of {ds_read || stage -> bar -> lgkm -> 8 MFMA -> bar}
    // mode 0: stage tile+2 (A3@P0, rest@P1) + vmcnt(6)@P3
    // mode 1: vmcnt(0)@P3;  mode 2: none
    auto doTile = [&](int tile, int mode) {
        const u16* Abuf = lds + (tile % 3) * BUF_EL;
        const u16* Bbuf = Abuf + A_EL;
        s16x8 a0, a1, a2, a3, b0, b1;

        auto rdA = [&](int kk) {
            const int ch0 = ((kk << 2) + fg);
            {const int r = wm*64 +  0 + fr; a0 = *(const s16x8*)(Abuf + r*64 + (ch0^(r&7))*8);}
            {const int r = wm*64 + 16 + fr; a1 = *(const s16x8*)(Abuf + r*64 + (ch0^(r&7))*8);}
            {const int r = wm*64 + 32 + fr; a2 = *(const s16x8*)(Abuf + r*64 + (ch0^(r&7))*8);}
            {const int r = wm*64 + 48 + fr; a3 = *(const s16x8*)(Abuf + r*64 + (ch0^(r&7))*8);}
        };
        auto rdB = [&](int kk, int np) {   // n-pair np: 0 -> n0,n1 ; 1 -> n2,n3
            const int ch0 = ((kk << 2) + fg);
            {const int r = wn*64 + (np*2+0)*16 + fr; b0 = *(const s16x8*)(Bbuf + r*64 + (ch0^(r&7))*8);}
            {const int r = wn*64 + (np*2+1)*16 + fr; b1 = *(const s16x8*)(Bbuf + r*64 + (ch0^(r&7))*8);}
        };
        auto fire = [&](int n0) {          // 8 MFMAs: acc[0..3][n0..n0+1]
            __builtin_amdgcn_s_setprio(1);
            acc[0][n0  ] = __builtin_amdgcn_mfma_f32_16x16x32_bf16(a0, b0, acc[0][n0  ], 0, 0, 0);
            acc[0][n0+1] = __builtin_amdgcn_mfma_f32_16x16x32_bf16(a0, b1, acc[0][n0+1], 0, 0, 0);
            acc[1][n0  ] = __builtin_amdgcn_mfma_f32_16x16x32_bf16(a1, b0, acc[1][n0  ], 0, 0, 0);
            acc[1][n0+1] = __builtin_amdgcn_mfma_f32_16x16x32_bf16(a1, b1, acc[1][n0+1], 0, 0, 0);
            acc[2][n0  ] = __builtin_amdgcn_mfma_f32_16x16x32_bf16(a2, b0, acc[2][n0  ], 0, 0, 0);
            acc[2][n0+1] = __builtin_amdgcn_mfma_f32_16x16x32_bf16(a2, b1, acc[2][n0+1], 0, 0, 0);
            acc[3][n0  ] = __builtin_amdgcn_mfma_f32_16x16x32_bf16(a3, b0, acc[3][n0  ], 0, 0, 0);
            acc[3][n0+1] = __builtin_amdgcn_mfma_f32_16x16x32_bf16(a3, b1, acc[3][n0+1], 0, 0, 0);
            __builtin_amdgcn_s_setprio(0);
        };
        auto barrier_in = [&]() {
            __builtin_amdgcn_s_barrier();
            asm volatile("s_waitcnt lgkmcnt(0)" ::: "memory");
            __builtin_amdgcn_sched_barrier(0);
        };

        // P0: A(kk=0) + B(n01,kk=0) ; stage A3
        rdA(0); rdB(0, 0);
        if (mode == 0) stageA3((tile + 2) % 3, tile + 2);
        barrier_in(); fire(0); __builtin_amdgcn_s_barrier();
        // P1: B(n23,kk=0) ; stage rest
        rdB(0, 1);
        if (mode == 0) stageRest((tile + 2) % 3, tile + 2);
        barrier_in(); fire(2); __builtin_amdgcn_s_barrier();
        // P2: A(kk=1) + B(n01,kk=1)
        rdA(1); rdB(1, 0);
        barrier_in(); fire(0); __builtin_amdgcn_s_barrier();
        // P3: B(n23,kk=1) ; counted vmcnt
        rdB(1, 1);
        if (mode == 0)      asm volatile("s_waitcnt vmcnt(6)" ::: "memory");
        else if (mode == 1) asm volatile("s_waitcnt vmcnt(0)" ::: "memory");
        barrier_in(); fire(2); __builtin_amdgcn_s_barrier();
    };

    const int NT = K >> 6;               // 16

    stageA3(0, 0); stageRest(0, 0);
    stageA3(1, 1); stageRest(1, 1);
    asm volatile("s_waitcnt vmcnt(6)" ::: "memory");   // tile 0 resident
    __builtin_amdgcn_s_barrier();

    for (int t = 0; t < NT - 2; ++t) doTile(t, 0);
    doTile(NT - 2, 1);
    doTile(NT - 1, 2);

    const int crow0 = row0 + wm * 64 + fg * 4;
    const int ccol0 = col0 + wn * 64 + fr;
    if (OUT_BF16) {
        u16* C = (u16*)Cout;
        #pragma unroll
        for (int m = 0; m < 4; ++m)
            #pragma unroll
            for (int n = 0; n < 4; ++n)
                #pragma unroll
                for (int j = 0; j < 4; ++j)
                    C[(size_t)(crow0 + m * 16 + j) * N + ccol0 + n * 16] =
                        f2bf(acc[m][n][j]);
    } else {
        float* C = (float*)Cout;
        #pragma unroll
        for (int m = 0; m < 4; ++m)
            #pragma unroll
            for (int n = 0; n < 4; ++n)
                #pragma unroll
                for (int j = 0; j < 4; ++j)
                    C[(size_t)(crow0 + m * 16 + j) * N + ccol0 + n * 16] =
                        acc[m][n][j];
    }
}

extern "C" void kernel_launch(void* const* d_in, const int* in_sizes, int n_in,
                              void* d_out, int out_size, void* d_ws, size_t ws_size,
                              hipStream_t stream) {
    const float* values = (const float*)d_in[0];
    // d_in[1] = queries: only its length matters (Lq == L)
    const unsigned char* mask = (const unsigned char*)d_in[2];
    const float* Win  = (const float*)d_in[3];
    const float* Wout = (const float*)d_in[4];
    float* out = (float*)d_out;

    const int M = BATCH * SEQL;   // 8192
    const int N = EMB;            // 1024
    const int K = EMB;            // 1024

    u16* VG    = (u16*)d_ws;                              // 8*1040*1024 (17 MB)
    u16* Attb  = VG + (size_t)BATCH * VROWS * EMB;        // 16 MB
    u16* Winb  = Attb + (size_t)M * EMB;                  // 2 MB
    u16* Woutb = Winb + (size_t)EMB * EMB;                // 2 MB (~37 MB total)

    // 1040 smoothing blocks + 1024 weight-cvt blocks
    smooth16<<<BATCH * (VROWS / 8) + 1024, 256, 0, stream>>>(
        values, mask, Win, Wout, VG, Winb, Woutb);

    dim3 ggrid((M / BM) * (N / BN));   // 256 WGs
    gemm_nt_pipe<true,  true ><<<ggrid, 512, 0, stream>>>(VG,   Winb,  Attb, M, N, K);
    gemm_nt_pipe<false, false><<<ggrid, 512, 0, stream>>>(Attb, Woutb, out,  M, N, K);
}

// Round 12
// 63.170 us; speedup vs baseline: 1.0491x; 1.0491x over previous
//
#include <hip/hip_runtime.h>
#include <hip/hip_bf16.h>
#include <cstddef>

// B=8, L=1024, E=1024, H=8, d=128
// out = BandedGaussianAttn(values @ Win^T) @ Wout^T
// Identity (R4..R10-proven): equal stds -> smoothing commutes with projection;
// per-head offset = row shift of GEMM1's A operand (BN=128 == one head).
// Pipeline:
//   smooth_blk16: 9-tap smoothing fp32->bf16, 16-row blocks (amp 1.5),
//                 8 rows x 8 cols/thread, LDS-hoisted mask, 16B stores
//                 + weight cvt tail blocks
//   GEMM1: Attb = VG(shifted rows) @ Winb^T  bf16->bf16  (R10-exact 2-phase)
//   GEMM2: out  = Attb @ Woutb^T             bf16->fp32  (R10-exact 2-phase)

#define BATCH 8
#define SEQL  1024
#define EMB   1024
#define VROWS 1040   // 65 groups x 16; VG row r holds smoothed source p = r-4

typedef unsigned short u16;
typedef __attribute__((ext_vector_type(8))) short s16x8;
typedef __attribute__((ext_vector_type(4))) float f32x4;
typedef __attribute__((ext_vector_type(8))) unsigned short u16x8;

#define GLOAD_LDS16(g, l)                                                     \
    __builtin_amdgcn_global_load_lds(                                         \
        (const __attribute__((address_space(1))) void*)(g),                   \
        (__attribute__((address_space(3))) void*)(l), 16, 0, 0)

__device__ __forceinline__ u16 f2bf(float f) {
    unsigned u = __builtin_bit_cast(unsigned, f);
    u += 0x7FFF + ((u >> 16) & 1);
    return (u16)(u >> 16);
}

__constant__ int c_ofs[8] = { -3, -2, -1, 0, 0, 1, 2, 3 };

// ---------- smooth_blk16: 9-tap smoothing, 16 VG rows per block ----------
// blocks [0, 520): b = blk&7, g = blk>>3 in [0,64] -> VG rows 16g..16g+15.
//   Block covers 24 input rows (amp 1.5). Thread: sub = tid>>7 picks 8-row
//   half, 8 cols; 16 row-loads x 2 float4; branchless f-factor from LDS
//   (mask+range pre-folded); interior groups skip clamping (uniform branch).
// blocks [520, 1544): fp32->bf16 cvt of Win/Wout.
__global__ __launch_bounds__(256) void smooth_blk16(
    const float* __restrict__ values, const unsigned char* __restrict__ mask,
    const float* __restrict__ wi, const float* __restrict__ wo,
    u16* __restrict__ VG, u16* __restrict__ wib, u16* __restrict__ wob)
{
    constexpr float W[9] = {
        1.3383022576488537e-04f, 4.431848411938008e-03f, 5.399096651318806e-02f,
        2.4197072451914337e-01f, 3.989422804014327e-01f, 2.4197072451914337e-01f,
        5.399096651318806e-02f,  4.431848411938008e-03f, 1.3383022576488537e-04f
    };
    const int blk = blockIdx.x;
    const int NSM = BATCH * (VROWS / 16);        // 520
    if (blk < NSM) {
        __shared__ float smf[24];
        const int b   = blk & 7;
        const int g   = blk >> 3;                // 0..64
        const int r0  = g * 16;                  // VG rows r0..r0+15
        const int v0  = r0 - 8;                  // covering input rows v0..v0+23
        const int tid = threadIdx.x;
        const unsigned char* mrow = mask + b * SEQL;

        if (tid < 24) {
            const int v  = v0 + tid;
            const int vc = v < 0 ? 0 : (v > SEQL - 1 ? SEQL - 1 : v);
            smf[tid] = ((unsigned)v < (unsigned)SEQL && !mrow[vc]) ? 1.f : 0.f;
        }
        __syncthreads();

        const int sub = tid >> 7;                // 0..1 (8-row half)
        const int ct  = (tid & 127) * 8;
        const float* vb = values + (size_t)b * SEQL * EMB + ct;
        const int base = r0 + sub * 8 - 8;       // thread's input rows base..base+15
        const bool bnd = (g == 0) | (g == 64);   // only boundary groups clamp

        f32x4 aA[8] = {}, aB[8] = {};
        #pragma unroll
        for (int i = 0; i < 16; ++i) {
            const int v  = base + i;
            const int vc = bnd ? (v < 0 ? 0 : (v > SEQL - 1 ? SEQL - 1 : v)) : v;
            const float f = smf[sub * 8 + i];
            const float4 xA = *(const float4*)(vb + (size_t)vc * EMB);
            const float4 xB = *(const float4*)(vb + (size_t)vc * EMB + 4);
            const float a0 = xA.x * f, a1 = xA.y * f, a2 = xA.z * f, a3 = xA.w * f;
            const float b0 = xB.x * f, b1 = xB.y * f, b2 = xB.z * f, b3 = xB.w * f;
            #pragma unroll
            for (int k = 0; k < 8; ++k) {
                const int j = i - k;             // compile-time tap index
                if (j < 0 || j > 8) continue;    // resolved at compile time
                const float w = W[j];
                aA[k][0] = fmaf(w, a0, aA[k][0]);
                aA[k][1] = fmaf(w, a1, aA[k][1]);
                aA[k][2] = fmaf(w, a2, aA[k][2]);
                aA[k][3] = fmaf(w, a3, aA[k][3]);
                aB[k][0] = fmaf(w, b0, aB[k][0]);
                aB[k][1] = fmaf(w, b1, aB[k][1]);
                aB[k][2] = fmaf(w, b2, aB[k][2]);
                aB[k][3] = fmaf(w, b3, aB[k][3]);
            }
        }
        u16* og = VG + (size_t)(b * VROWS + r0 + sub * 8) * EMB + ct;
        #pragma unroll
        for (int k = 0; k < 8; ++k) {
            u16x8 o;
            o[0] = f2bf(aA[k][0]); o[1] = f2bf(aA[k][1]);
            o[2] = f2bf(aA[k][2]); o[3] = f2bf(aA[k][3]);
            o[4] = f2bf(aB[k][0]); o[5] = f2bf(aB[k][1]);
            o[6] = f2bf(aB[k][2]); o[7] = f2bf(aB[k][3]);
            *(u16x8*)(og + (size_t)k * EMB) = o;
        }
    } else {
        const int k = (blk - NSM) * 256 + threadIdx.x;   // 0..262143
        const float* src = (k < 131072) ? wi : wo;
        u16* dst = (k < 131072) ? wib : wob;
        const size_t off = (size_t)(k & 131071) * 8;
        const float4 a = *(const float4*)(src + off);
        const float4 b4 = *(const float4*)(src + off + 4);
        u16x8 o;
        o[0] = f2bf(a.x);  o[1] = f2bf(a.y);  o[2] = f2bf(a.z);  o[3] = f2bf(a.w);
        o[4] = f2bf(b4.x); o[5] = f2bf(b4.y); o[6] = f2bf(b4.z); o[7] = f2bf(b4.w);
        *(u16x8*)(dst + off) = o;
    }
}

// ---------- pipelined bf16 MFMA GEMM: C[M,N] = A[M,K]*B[N,K]^T (R10-exact) ----------
// BM=256 BN=128 BK=64, 512 thr / 8 waves (4M x 2N, per-wave 64x64).
// 3-buffer LDS, 2 fine phases per K-tile, vmcnt(6) counted waits,
// T2 XOR-chunk swizzle, T5 setprio, T1 XCD swizzle.
constexpr int BM = 256, BN = 128, BK = 64;
constexpr int A_EL = BM * BK;
constexpr int B_EL = BN * BK;
constexpr int BUF_EL = A_EL + B_EL;      // 48 KB x3 = 144 KB

template <bool OUT_BF16, bool SHIFTED>
__global__ __launch_bounds__(512, 2) void gemm_nt_pipe(
    const u16* __restrict__ A, const u16* __restrict__ B,
    void* __restrict__ Cout, int M, int N, int K)
{
    __shared__ u16 lds[3 * BUF_EL];

    const int tid  = threadIdx.x;
    const int lane = tid & 63;
    const int wave = tid >> 6;

    const int nwg = gridDim.x;
    const int bid = blockIdx.x;
    const int swz = (bid & 7) * (nwg >> 3) + (bid >> 3);
    const int ntn = N >> 7;
    const int row0 = (swz / ntn) * BM;
    const int col0 = (swz % ntn) * BN;

    int arow0;
    if (SHIFTED) {
        const int b  = row0 >> 10;            // BM=256 | 1024: no batch straddle
        const int q0 = row0 & (SEQL - 1);
        arow0 = b * VROWS + q0 + 4 + c_ofs[col0 >> 7];
    } else {
        arow0 = row0;
    }
    const u16* Ab = A + (size_t)arow0 * K;
    const u16* Bb = B + (size_t)col0 * K;

    const int wm = wave >> 1;
    const int wn = wave & 1;
    const int fr = lane & 15;
    const int fg = lane >> 4;

    const int srow   = tid >> 3;
    const int schunk = tid & 7;

    f32x4 acc[4][4] = {};
    s16x8 af[4][2], bf0[2][2], bf1[2][2];

    auto stageA3 = [&](int bsel, int kt) {
        u16* Abuf = lds + bsel * BUF_EL;
        const int k0 = kt << 6;
        #pragma unroll
        for (int c = 0; c < 3; ++c) {
            const int row = c * 64 + srow;
            const int sc  = (schunk ^ (row & 7)) << 3;
            GLOAD_LDS16(Ab + (size_t)row * K + k0 + sc, Abuf + c * 4096 + wave * 512);
        }
    };
    auto stageRest = [&](int bsel, int kt) {
        u16* Abuf = lds + bsel * BUF_EL;
        u16* Bbuf = Abuf + A_EL;
        const int k0 = kt << 6;
        {
            const int row = 192 + srow;
            const int sc  = (schunk ^ (row & 7)) << 3;
            GLOAD_LDS16(Ab + (size_t)row * K + k0 + sc, Abuf + 3 * 4096 + wave * 512);
        }
        #pragma unroll
        for (int c = 0; c < 2; ++c) {
            const int row = c * 64 + srow;
            const int sc  = (schunk ^ (row & 7)) << 3;
            GLOAD_LDS16(Bb + (size_t)row * K + k0 + sc, Bbuf + c * 4096 + wave * 512);
        }
    };

    auto phase0 = [&](int tile, bool doStage) {
        const u16* Abuf = lds + (tile % 3) * BUF_EL;
        const u16* Bbuf = Abuf + A_EL;
        #pragma unroll
        for (int m = 0; m < 4; ++m)
            #pragma unroll
            for (int kk = 0; kk < 2; ++kk) {
                const int row = wm * 64 + m * 16 + fr;
                const int ch  = ((kk << 2) + fg) ^ (row & 7);
                af[m][kk] = *(const s16x8*)(Abuf + row * 64 + ch * 8);
            }
        #pragma unroll
        for (int n = 0; n < 2; ++n)
            #pragma unroll
            for (int kk = 0; kk < 2; ++kk) {
                const int row = wn * 64 + n * 16 + fr;
                const int ch  = ((kk << 2) + fg) ^ (row & 7);
                bf0[n][kk] = *(const s16x8*)(Bbuf + row * 64 + ch * 8);
            }
        if (doStage) stageA3((tile + 2) % 3, tile + 2);
        __builtin_amdgcn_s_barrier();
        asm volatile("s_waitcnt lgkmcnt(0)" ::: "memory");
        __builtin_amdgcn_sched_barrier(0);
        __builtin_amdgcn_s_setprio(1);
        #pragma unroll
        for (int m = 0; m < 4; ++m)
            #pragma unroll
            for (int n = 0; n < 2; ++n)
                #pragma unroll
                for (int kk = 0; kk < 2; ++kk)
                    acc[m][n] = __builtin_amdgcn_mfma_f32_16x16x32_bf16(
                        af[m][kk], bf0[n][kk], acc[m][n], 0, 0, 0);
        __builtin_amdgcn_s_setprio(0);
        __builtin_amdgcn_s_barrier();
    };

    auto phase1 = [&](int tile, int mode /*0: stage+vm6, 1: vm0, 2: none*/) {
        const u16* Abuf = lds + (tile % 3) * BUF_EL;
        const u16* Bbuf = Abuf + A_EL;
        #pragma unroll
        for (int n = 0; n < 2; ++n)
            #pragma unroll
            for (int kk = 0; kk < 2; ++kk) {
                const int row = wn * 64 + (2 + n) * 16 + fr;
                const int ch  = ((kk << 2) + fg) ^ (row & 7);
                bf1[n][kk] = *(const s16x8*)(Bbuf + row * 64 + ch * 8);
            }
        if (mode == 0) {
            stageRest((tile + 2) % 3, tile + 2);
            asm volatile("s_waitcnt vmcnt(6)" ::: "memory");
        } else if (mode == 1) {
            asm volatile("s_waitcnt vmcnt(0)" ::: "memory");
        }
        __builtin_amdgcn_s_barrier();
        asm volatile("s_waitcnt lgkmcnt(0)" ::: "memory");
        __builtin_amdgcn_sched_barrier(0);
        __builtin_amdgcn_s_setprio(1);
        #pragma unroll
        for (int m = 0; m < 4; ++m)
            #pragma unroll
            for (int n = 0; n < 2; ++n)
                #pragma unroll
                for (int kk = 0; kk < 2; ++kk)
                    acc[m][2 + n] = __builtin_amdgcn_mfma_f32_16x16x32_bf16(
                        af[m][kk], bf1[n][kk], acc[m][2 + n], 0, 0, 0);
        __builtin_amdgcn_s_setprio(0);
        __builtin_amdgcn_s_barrier();
    };

    const int NT = K >> 6;

    stageA3(0, 0); stageRest(0, 0);
    stageA3(1, 1); stageRest(1, 1);
    asm volatile("s_waitcnt vmcnt(6)" ::: "memory");
    __builtin_amdgcn_s_barrier();

    for (int t = 0; t < NT - 2; ++t) { phase0(t, true); phase1(t, 0); }
    phase0(NT - 2, false); phase1(NT - 2, 1);
    phase0(NT - 1, false); phase1(NT - 1, 2);

    const int crow0 = row0 + wm * 64 + fg * 4;
    const int ccol0 = col0 + wn * 64 + fr;
    if (OUT_BF16) {
        u16* C = (u16*)Cout;
        #pragma unroll
        for (int m = 0; m < 4; ++m)
            #pragma unroll
            for (int n = 0; n < 4; ++n)
                #pragma unroll
                for (int j = 0; j < 4; ++j)
                    C[(size_t)(crow0 + m * 16 + j) * N + ccol0 + n * 16] =
                        f2bf(acc[m][n][j]);
    } else {
        float* C = (float*)Cout;
        #pragma unroll
        for (int m = 0; m < 4; ++m)
            #pragma unroll
            for (int n = 0; n < 4; ++n)
                #pragma unroll
                for (int j = 0; j < 4; ++j)
                    C[(size_t)(crow0 + m * 16 + j) * N + ccol0 + n * 16] =
                        acc[m][n][j];
    }
}

extern "C" void kernel_launch(void* const* d_in, const int* in_sizes, int n_in,
                              void* d_out, int out_size, void* d_ws, size_t ws_size,
                              hipStream_t stream) {
    const float* values = (const float*)d_in[0];
    // d_in[1] = queries: only its length matters (Lq == L)
    const unsigned char* mask = (const unsigned char*)d_in[2];
    const float* Win  = (const float*)d_in[3];
    const float* Wout = (const float*)d_in[4];
    float* out = (float*)d_out;

    const int M = BATCH * SEQL;   // 8192
    const int N = EMB;            // 1024
    const int K = EMB;            // 1024

    u16* VG    = (u16*)d_ws;                              // 8*1040*1024 (17 MB)
    u16* Attb  = VG + (size_t)BATCH * VROWS * EMB;        // 16 MB
    u16* Winb  = Attb + (size_t)M * EMB;                  // 2 MB
    u16* Woutb = Winb + (size_t)EMB * EMB;                // 2 MB (~37 MB total)

    // 520 smoothing blocks + 1024 weight-cvt blocks
    smooth_blk16<<<BATCH * (VROWS / 16) + 1024, 256, 0, stream>>>(
        values, mask, Win, Wout, VG, Winb, Woutb);

    dim3 ggrid((M / BM) * (N / BN));   // 256 WGs
    gemm_nt_pipe<true,  true ><<<ggrid, 512, 0, stream>>>(VG,   Winb,  Attb, M, N, K);
    gemm_nt_pipe<false, false><<<ggrid, 512, 0, stream>>>(Attb, Woutb, out,  M, N, K);
}

// Round 13
// 61.026 us; speedup vs baseline: 1.0859x; 1.0351x over previous
//
#include <hip/hip_runtime.h>
#include <hip/hip_bf16.h>
#include <cstddef>

// B=8, L=1024, E=1024, H=8, d=128
// out = BandedGaussianAttn(values @ Win^T) @ Wout^T
// Identity (R4..R12-proven): equal stds -> smoothing commutes with projection;
// per-head offset = row shift of GEMM1's A operand (BN=128 == one head).
// Pipeline:
//   smooth_lds: 9-tap smoothing fp32->bf16 via global_load_lds staged LDS
//               (32 out rows x 256 cols/block, 40KB LDS, amp 1.25)
//               + weight cvt tail blocks
//   GEMM1: Attb = VG(shifted rows) @ Winb^T  bf16->bf16  (R10-exact)
//   GEMM2: out  = Attb @ Woutb^T             bf16->fp32  (R10-exact)

#define BATCH 8
#define SEQL  1024
#define EMB   1024
#define VROWS 1056   // 33 x 32; VG row r holds smoothed source p = r-4

typedef unsigned short u16;
typedef __attribute__((ext_vector_type(8))) short s16x8;
typedef __attribute__((ext_vector_type(4))) float f32x4;
typedef __attribute__((ext_vector_type(8))) unsigned short u16x8;
typedef __attribute__((ext_vector_type(4))) unsigned short u16x4;

#define GLOAD_LDS16(g, l)                                                     \
    __builtin_amdgcn_global_load_lds(                                         \
        (const __attribute__((address_space(1))) void*)(g),                   \
        (__attribute__((address_space(3))) void*)(l), 16, 0, 0)

__device__ __forceinline__ u16 f2bf(float f) {
    unsigned u = __builtin_bit_cast(unsigned, f);
    u += 0x7FFF + ((u >> 16) & 1);
    return (u16)(u >> 16);
}

__constant__ int c_ofs[8] = { -3, -2, -1, 0, 0, 1, 2, 3 };

// ---------- smooth_lds: 9-tap smoothing via async-staged LDS strip ----------
// blocks [0, 1056): b = blk&7; t = blk>>3; g = t>>2 (row group 0..32),
//   cg = t&3 (256-col window). Stage 40 input rows x 256 cols fp32 (40KB)
//   with 10x global_load_lds(16B)/thread; validity (range+mask) pre-folded
//   into smf[40]; compute: thread = (rg 0..3) x (cc 0..63): 8 out rows x
//   4 cols from 16 ds_read_b128. Boundary rows clamp source addr; smf zeroes.
// blocks [1056, 2080): fp32->bf16 cvt of Win/Wout.
__global__ __launch_bounds__(256) void smooth_lds(
    const float* __restrict__ values, const unsigned char* __restrict__ mask,
    const float* __restrict__ wi, const float* __restrict__ wo,
    u16* __restrict__ VG, u16* __restrict__ wib, u16* __restrict__ wob)
{
    constexpr float W[9] = {
        1.3383022576488537e-04f, 4.431848411938008e-03f, 5.399096651318806e-02f,
        2.4197072451914337e-01f, 3.989422804014327e-01f, 2.4197072451914337e-01f,
        5.399096651318806e-02f,  4.431848411938008e-03f, 1.3383022576488537e-04f
    };
    __shared__ float sx[40 * 256];     // 40KB staged fp32 strip
    __shared__ float smf[40];          // per-row validity factor

    const int blk = blockIdx.x;
    const int NSM = BATCH * 33 * 4;    // 1056
    const int tid = threadIdx.x;
    if (blk < NSM) {
        const int b  = blk & 7;
        const int t  = blk >> 3;       // 0..131
        const int g  = t >> 2;         // 0..32
        const int cg = t & 3;          // 0..3
        const int r0 = g * 32;         // VG rows r0..r0+31
        const int v0 = r0 - 8;         // staged input rows v0..v0+39
        const int c0 = cg * 256;
        const float* vbase = values + (size_t)b * SEQL * EMB + c0;
        const unsigned char* mrow = mask + b * SEQL;

        // async stage: chunk n = c*256+tid -> LDS float offset n*4
        #pragma unroll
        for (int c = 0; c < 10; ++c) {
            const int n    = c * 256 + tid;
            const int row  = n >> 6;
            const int col4 = (n & 63) * 4;
            const int v    = v0 + row;
            const int vc   = v < 0 ? 0 : (v > SEQL - 1 ? SEQL - 1 : v);
            GLOAD_LDS16(vbase + (size_t)vc * EMB + col4,
                        sx + c * 1024 + (tid >> 6) * 256);
        }
        if (tid < 40) {
            const int v  = v0 + tid;
            const int vc = v < 0 ? 0 : (v > SEQL - 1 ? SEQL - 1 : v);
            smf[tid] = ((unsigned)v < (unsigned)SEQL && !mrow[vc]) ? 1.f : 0.f;
        }
        asm volatile("s_waitcnt vmcnt(0)" ::: "memory");
        __syncthreads();

        const int rg = tid >> 6;       // 0..3 -> out rows rg*8..+7
        const int cc = tid & 63;       // col chunk (4 floats)
        const int rl0 = rg * 8;
        f32x4 acc[8] = {};
        #pragma unroll
        for (int i = 0; i < 16; ++i) { // LDS rows rl0..rl0+15
            const f32x4 xr = *(const f32x4*)&sx[(rl0 + i) * 256 + cc * 4];
            const float f = smf[rl0 + i];
            const float x0 = xr[0] * f, x1 = xr[1] * f, x2 = xr[2] * f, x3 = xr[3] * f;
            #pragma unroll
            for (int k = 0; k < 8; ++k) {
                const int j = i - k;            // compile-time tap index
                if (j < 0 || j > 8) continue;   // resolved at compile time
                const float w = W[j];
                acc[k][0] = fmaf(w, x0, acc[k][0]);
                acc[k][1] = fmaf(w, x1, acc[k][1]);
                acc[k][2] = fmaf(w, x2, acc[k][2]);
                acc[k][3] = fmaf(w, x3, acc[k][3]);
            }
        }
        u16* og = VG + (size_t)(b * VROWS + r0 + rl0) * EMB + c0 + cc * 4;
        #pragma unroll
        for (int k = 0; k < 8; ++k) {
            u16x4 o;
            o[0] = f2bf(acc[k][0]); o[1] = f2bf(acc[k][1]);
            o[2] = f2bf(acc[k][2]); o[3] = f2bf(acc[k][3]);
            *(u16x4*)(og + (size_t)k * EMB) = o;
        }
    } else {
        const int k = (blk - NSM) * 256 + tid;   // 0..262143
        const float* src = (k < 131072) ? wi : wo;
        u16* dst = (k < 131072) ? wib : wob;
        const size_t off = (size_t)(k & 131071) * 8;
        const float4 a = *(const float4*)(src + off);
        const float4 b4 = *(const float4*)(src + off + 4);
        u16x8 o;
        o[0] = f2bf(a.x);  o[1] = f2bf(a.y);  o[2] = f2bf(a.z);  o[3] = f2bf(a.w);
        o[4] = f2bf(b4.x); o[5] = f2bf(b4.y); o[6] = f2bf(b4.z); o[7] = f2bf(b4.w);
        *(u16x8*)(dst + off) = o;
    }
}

// ---------- pipelined bf16 MFMA GEMM: C[M,N] = A[M,K]*B[N,K]^T (R10-exact) ----------
// BM=256 BN=128 BK=64, 512 thr / 8 waves (4M x 2N, per-wave 64x64).
// 3-buffer LDS, 2 fine phases per K-tile, vmcnt(6) counted waits,
// T2 XOR-chunk swizzle, T5 setprio, T1 XCD swizzle.
constexpr int BM = 256, BN = 128, BK = 64;
constexpr int A_EL = BM * BK;
constexpr int B_EL = BN * BK;
constexpr int BUF_EL = A_EL + B_EL;      // 48 KB x3 = 144 KB

template <bool OUT_BF16, bool SHIFTED>
__global__ __launch_bounds__(512, 2) void gemm_nt_pipe(
    const u16* __restrict__ A, const u16* __restrict__ B,
    void* __restrict__ Cout, int M, int N, int K)
{
    __shared__ u16 lds[3 * BUF_EL];

    const int tid  = threadIdx.x;
    const int lane = tid & 63;
    const int wave = tid >> 6;

    const int nwg = gridDim.x;
    const int bid = blockIdx.x;
    const int swz = (bid & 7) * (nwg >> 3) + (bid >> 3);
    const int ntn = N >> 7;
    const int row0 = (swz / ntn) * BM;
    const int col0 = (swz % ntn) * BN;

    int arow0;
    if (SHIFTED) {
        const int b  = row0 >> 10;            // BM=256 | 1024: no batch straddle
        const int q0 = row0 & (SEQL - 1);
        arow0 = b * VROWS + q0 + 4 + c_ofs[col0 >> 7];
    } else {
        arow0 = row0;
    }
    const u16* Ab = A + (size_t)arow0 * K;
    const u16* Bb = B + (size_t)col0 * K;

    const int wm = wave >> 1;
    const int wn = wave & 1;
    const int fr = lane & 15;
    const int fg = lane >> 4;

    const int srow   = tid >> 3;
    const int schunk = tid & 7;

    f32x4 acc[4][4] = {};
    s16x8 af[4][2], bf0[2][2], bf1[2][2];

    auto stageA3 = [&](int bsel, int kt) {
        u16* Abuf = lds + bsel * BUF_EL;
        const int k0 = kt << 6;
        #pragma unroll
        for (int c = 0; c < 3; ++c) {
            const int row = c * 64 + srow;
            const int sc  = (schunk ^ (row & 7)) << 3;
            GLOAD_LDS16(Ab + (size_t)row * K + k0 + sc, Abuf + c * 4096 + wave * 512);
        }
    };
    auto stageRest = [&](int bsel, int kt) {
        u16* Abuf = lds + bsel * BUF_EL;
        u16* Bbuf = Abuf + A_EL;
        const int k0 = kt << 6;
        {
            const int row = 192 + srow;
            const int sc  = (schunk ^ (row & 7)) << 3;
            GLOAD_LDS16(Ab + (size_t)row * K + k0 + sc, Abuf + 3 * 4096 + wave * 512);
        }
        #pragma unroll
        for (int c = 0; c < 2; ++c) {
            const int row = c * 64 + srow;
            const int sc  = (schunk ^ (row & 7)) << 3;
            GLOAD_LDS16(Bb + (size_t)row * K + k0 + sc, Bbuf + c * 4096 + wave * 512);
        }
    };

    auto phase0 = [&](int tile, bool doStage) {
        const u16* Abuf = lds + (tile % 3) * BUF_EL;
        const u16* Bbuf = Abuf + A_EL;
        #pragma unroll
        for (int m = 0; m < 4; ++m)
            #pragma unroll
            for (int kk = 0; kk < 2; ++kk) {
                const int row = wm * 64 + m * 16 + fr;
                const int ch  = ((kk << 2) + fg) ^ (row & 7);
                af[m][kk] = *(const s16x8*)(Abuf + row * 64 + ch * 8);
            }
        #pragma unroll
        for (int n = 0; n < 2; ++n)
            #pragma unroll
            for (int kk = 0; kk < 2; ++kk) {
                const int row = wn * 64 + n * 16 + fr;
                const int ch  = ((kk << 2) + fg) ^ (row & 7);
                bf0[n][kk] = *(const s16x8*)(Bbuf + row * 64 + ch * 8);
            }
        if (doStage) stageA3((tile + 2) % 3, tile + 2);
        __builtin_amdgcn_s_barrier();
        asm volatile("s_waitcnt lgkmcnt(0)" ::: "memory");
        __builtin_amdgcn_sched_barrier(0);
        __builtin_amdgcn_s_setprio(1);
        #pragma unroll
        for (int m = 0; m < 4; ++m)
            #pragma unroll
            for (int n = 0; n < 2; ++n)
                #pragma unroll
                for (int kk = 0; kk < 2; ++kk)
                    acc[m][n] = __builtin_amdgcn_mfma_f32_16x16x32_bf16(
                        af[m][kk], bf0[n][kk], acc[m][n], 0, 0, 0);
        __builtin_amdgcn_s_setprio(0);
        __builtin_amdgcn_s_barrier();
    };

    auto phase1 = [&](int tile, int mode /*0: stage+vm6, 1: vm0, 2: none*/) {
        const u16* Abuf = lds + (tile % 3) * BUF_EL;
        const u16* Bbuf = Abuf + A_EL;
        #pragma unroll
        for (int n = 0; n < 2; ++n)
            #pragma unroll
            for (int kk = 0; kk < 2; ++kk) {
                const int row = wn * 64 + (2 + n) * 16 + fr;
                const int ch  = ((kk << 2) + fg) ^ (row & 7);
                bf1[n][kk] = *(const s16x8*)(Bbuf + row * 64 + ch * 8);
            }
        if (mode == 0) {
            stageRest((tile + 2) % 3, tile + 2);
            asm volatile("s_waitcnt vmcnt(6)" ::: "memory");
        } else if (mode == 1) {
            asm volatile("s_waitcnt vmcnt(0)" ::: "memory");
        }
        __builtin_amdgcn_s_barrier();
        asm volatile("s_waitcnt lgkmcnt(0)" ::: "memory");
        __builtin_amdgcn_sched_barrier(0);
        __builtin_amdgcn_s_setprio(1);
        #pragma unroll
        for (int m = 0; m < 4; ++m)
            #pragma unroll
            for (int n = 0; n < 2; ++n)
                #pragma unroll
                for (int kk = 0; kk < 2; ++kk)
                    acc[m][2 + n] = __builtin_amdgcn_mfma_f32_16x16x32_bf16(
                        af[m][kk], bf1[n][kk], acc[m][2 + n], 0, 0, 0);
        __builtin_amdgcn_s_setprio(0);
        __builtin_amdgcn_s_barrier();
    };

    const int NT = K >> 6;

    stageA3(0, 0); stageRest(0, 0);
    stageA3(1, 1); stageRest(1, 1);
    asm volatile("s_waitcnt vmcnt(6)" ::: "memory");
    __builtin_amdgcn_s_barrier();

    for (int t = 0; t < NT - 2; ++t) { phase0(t, true); phase1(t, 0); }
    phase0(NT - 2, false); phase1(NT - 2, 1);
    phase0(NT - 1, false); phase1(NT - 1, 2);

    const int crow0 = row0 + wm * 64 + fg * 4;
    const int ccol0 = col0 + wn * 64 + fr;
    if (OUT_BF16) {
        u16* C = (u16*)Cout;
        #pragma unroll
        for (int m = 0; m < 4; ++m)
            #pragma unroll
            for (int n = 0; n < 4; ++n)
                #pragma unroll
                for (int j = 0; j < 4; ++j)
                    C[(size_t)(crow0 + m * 16 + j) * N + ccol0 + n * 16] =
                        f2bf(acc[m][n][j]);
    } else {
        float* C = (float*)Cout;
        #pragma unroll
        for (int m = 0; m < 4; ++m)
            #pragma unroll
            for (int n = 0; n < 4; ++n)
                #pragma unroll
                for (int j = 0; j < 4; ++j)
                    C[(size_t)(crow0 + m * 16 + j) * N + ccol0 + n * 16] =
                        acc[m][n][j];
    }
}

extern "C" void kernel_launch(void* const* d_in, const int* in_sizes, int n_in,
                              void* d_out, int out_size, void* d_ws, size_t ws_size,
                              hipStream_t stream) {
    const float* values = (const float*)d_in[0];
    // d_in[1] = queries: only its length matters (Lq == L)
    const unsigned char* mask = (const unsigned char*)d_in[2];
    const float* Win  = (const float*)d_in[3];
    const float* Wout = (const float*)d_in[4];
    float* out = (float*)d_out;

    const int M = BATCH * SEQL;   // 8192
    const int N = EMB;            // 1024
    const int K = EMB;            // 1024

    u16* VG    = (u16*)d_ws;                              // 8*1056*1024 (17.3 MB)
    u16* Attb  = VG + (size_t)BATCH * VROWS * EMB;        // 16 MB
    u16* Winb  = Attb + (size_t)M * EMB;                  // 2 MB
    u16* Woutb = Winb + (size_t)EMB * EMB;                // 2 MB (~37 MB total)

    // 1056 smoothing blocks + 1024 weight-cvt blocks
    smooth_lds<<<1056 + 1024, 256, 0, stream>>>(
        values, mask, Win, Wout, VG, Winb, Woutb);

    dim3 ggrid((M / BM) * (N / BN));   // 256 WGs
    gemm_nt_pipe<true,  true ><<<ggrid, 512, 0, stream>>>(VG,   Winb,  Attb, M, N, K);
    gemm_nt_pipe<false, false><<<ggrid, 512, 0, stream>>>(Attb, Woutb, out,  M, N, K);
}